// Round 1
// 496.710 us; speedup vs baseline: 1.2418x; 1.2418x over previous
//
#include <hip/hip_runtime.h>
#include <hip/hip_bf16.h>
#include <cstdint>

// MinGRU: g=sigmoid(xWg^T+bg), c=tanh(xWh^T+bh), h_t = g*h_{t-1} + (1-g)*c
// B=8, L=4096, D=1024.  M = B*L = 32768, K = E = 1024.
//
// R4 structure (from R3):
//  - plain fp16 GEMM: x->fp16 RTNE, W->fp16 RTNE, ONE mfma_f32_16x16x32_f16 per
//    output per K-step (was split-bf16 with 3 products -> -67% MFMA work).
//    z-error std ~2e-4, below the fp16 g/c-storage error floor (absmax 2^-8).
//  - B k-chunk XOR swizzle (kq ^= (row>>1)&3) applied to BOTH the per-lane
//    global source of global_load_lds (LDS stays linear) and the ds_read
//    address: kills the 8-way bank conflict on B-fragment reads (was 3.35e7).
//  - z-merged: one block computes BOTH g and c tiles (x staged once for both)
//  - grid swizzled e-major: consecutive blocks share x m-tile
//  - epilogue via LDS fp32 tile -> coalesced fp16x8 (16B/lane) stores
//  - g,c stored fp16; chunked scan LCH=32, NCH=128 (unchanged)
// ws layout: Wg fp16 2M | Wh fp16 2M | (2 spare) | g fp16 64MiB | c fp16 64MiB
//            | Ac 4M | Bc 4M | Hst 4M

using u16   = unsigned short;
using f32x4 = __attribute__((ext_vector_type(4))) float;
using h16x4 = __attribute__((ext_vector_type(4))) _Float16;
using h16x8 = __attribute__((ext_vector_type(8))) _Float16;

#define M_TOTAL 32768
#define K_DIM   1024
#define E_DIM   1024
#define LCH     32     // scan chunk length
#define NCH     128    // chunks per sequence (4096/32)

// ---------------- W pre-convert: fp32 -> fp16 (RTNE) ----------------
__global__ void conv_w(const float* __restrict__ wg, const float* __restrict__ wh,
                       u16* __restrict__ dst_base, int n4) {
    const float* w = blockIdx.y ? wh : wg;
    u16* dst = dst_base + (size_t)blockIdx.y * 1024 * 1024;  // elements
    int i = blockIdx.x * blockDim.x + threadIdx.x;
    if (i >= n4) return;
    f32x4 f = ((const f32x4*)w)[i];
    h16x4 h;
#pragma unroll
    for (int c = 0; c < 4; ++c) h[c] = (_Float16)f[c];
    ((h16x4*)dst)[i] = h;
}

__device__ inline float fast_sigmoid(float z) {
    return 1.f / (1.f + __expf(-z));
}
__device__ inline float fast_tanh(float z) {
    return 1.f - 2.f / (__expf(2.f * z) + 1.f);  // saturates correctly
}

// ---------------- GEMM + activation (z-merged, dual accumulators) ----------------
// grid: (E/128, M/128)  [e-major: consecutive blocks share the x m-tile]
__global__ __launch_bounds__(256, 2) void gemm_act(
    const float* __restrict__ x,
    const u16* __restrict__ wg_h, const u16* __restrict__ wh_h,
    const float* __restrict__ bg, const float* __restrict__ bh,
    _Float16* __restrict__ g_out, _Float16* __restrict__ c_out) {

    const int e0 = blockIdx.x * 128;
    const int m0 = blockIdx.y * 128;

    // Staging buffers union'd with the epilogue fp32 tile (epilogue runs after
    // the final sync, so reuse is safe). A padded stride 40: rows 80B apart ->
    // 2-way bank alias only (free). B rows unpadded 64B (lds-dma requirement);
    // k-chunk XOR swizzle breaks its 8-way conflict instead.
    __shared__ __align__(16) union SM {
        struct {
            u16 A[128 * 40];    // x tile as fp16, padded stride 40
            u16 B[2][128 * 32]; // Wg, Wh fp16 (unpadded for lds-dma)
        } s;
        float tile[128][132];
    } sm;

    const int tid  = threadIdx.x;
    const int lane = tid & 63;
    const int wave = tid >> 6;
    const int wr = wave >> 1, wc = wave & 1;  // 2x2 wave grid, each 64x64
    const int lr = lane & 15;                 // row/col within 16
    const int kg = lane >> 4;                 // k-group (quad)

    const u16* __restrict__ Wptr[2] = {wg_h, wh_h};

    f32x4 accg[4][4], acch[4][4];
#pragma unroll
    for (int tr = 0; tr < 4; ++tr)
#pragma unroll
        for (int tc = 0; tc < 4; ++tc) {
            accg[tr][tc] = (f32x4){0.f, 0.f, 0.f, 0.f};
            acch[tr][tc] = (f32x4){0.f, 0.f, 0.f, 0.f};
        }

    for (int kt = 0; kt < K_DIM / 32; ++kt) {
        __syncthreads();  // previous iter's LDS reads done before overwrite

        // ---- stage B (2 weight regions) via async global->LDS, 16B chunks ----
        // Source k-chunk is XOR-swizzled per row; LDS destination stays linear
        // (global_load_lds writes base+lane*16). Chunks permute within one 64B
        // row window, so coalescing is unaffected.
#pragma unroll
        for (int rgn = 0; rgn < 2; ++rgn) {
#pragma unroll
            for (int j = 0; j < 2; ++j) {
                int ch  = tid + 256 * j;      // 512 chunks of 16B = 8KB
                int row = ch >> 2;            // e-row 0..127
                int kq  = ch & 3;             // 16B k-chunk slot
                int kqs = kq ^ ((row >> 1) & 3);  // source chunk (involution)
                size_t goff = (size_t)(e0 + row) * K_DIM + kt * 32 + kqs * 8;
                __builtin_amdgcn_global_load_lds(
                    (const __attribute__((address_space(1))) void*)(Wptr[rgn] + goff),
                    (__attribute__((address_space(3))) void*)(&sm.s.B[rgn][ch * 8]), 16, 0, 0);
            }
        }

        // ---- stage A (x rows), convert fp32 -> fp16 ----
#pragma unroll
        for (int j = 0; j < 4; ++j) {
            int q   = tid + 256 * j;          // 1024 float4s = 128x32 fp32
            int row = q >> 3;                 // m-row 0..127
            int kq  = q & 7;                  // float4 within row
            f32x4 f = *(const f32x4*)(x + (size_t)(m0 + row) * K_DIM + kt * 32 + kq * 4);
            h16x4 h;
#pragma unroll
            for (int c = 0; c < 4; ++c) h[c] = (_Float16)f[c];
            *(h16x4*)&sm.s.A[row * 40 + kq * 4] = h;
        }

        __syncthreads();

        // ---- fragments + MFMA (A frags shared across both GEMMs) ----
        h16x8 ah[4];
#pragma unroll
        for (int tr = 0; tr < 4; ++tr) {
            int r = wr * 64 + tr * 16 + lr;
            ah[tr] = *(const h16x8*)&sm.s.A[r * 40 + kg * 8];
        }
#pragma unroll
        for (int tc = 0; tc < 4; ++tc) {
            int e   = wc * 64 + tc * 16 + lr;
            int kgs = kg ^ ((e >> 1) & 3);    // swizzled slot holding chunk kg
            h16x8 bgv = *(const h16x8*)&sm.s.B[0][e * 32 + kgs * 8];
            h16x8 bhv = *(const h16x8*)&sm.s.B[1][e * 32 + kgs * 8];
#pragma unroll
            for (int tr = 0; tr < 4; ++tr) {
                accg[tr][tc] = __builtin_amdgcn_mfma_f32_16x16x32_f16(ah[tr], bgv, accg[tr][tc], 0, 0, 0);
                acch[tr][tc] = __builtin_amdgcn_mfma_f32_16x16x32_f16(ah[tr], bhv, acch[tr][tc], 0, 0, 0);
            }
        }
    }

    // ---- epilogue: bias+activation -> LDS fp32 tile -> coalesced fp16x8 store ----
#pragma unroll
    for (int arr = 0; arr < 2; ++arr) {
        __syncthreads();  // LDS (staging or previous tile) free for reuse
#pragma unroll
        for (int tc = 0; tc < 4; ++tc) {
            int el = wc * 64 + tc * 16 + lr;
            float bv = (arr ? bh : bg)[e0 + el];
#pragma unroll
            for (int tr = 0; tr < 4; ++tr) {
                int rb = wr * 64 + tr * 16 + kg * 4;
#pragma unroll
                for (int i = 0; i < 4; ++i) {
                    float z = (arr ? acch : accg)[tr][tc][i] + bv;
                    sm.tile[rb + i][el] = arr ? fast_tanh(z) : fast_sigmoid(z);
                }
            }
        }
        __syncthreads();
        _Float16* outp = arr ? c_out : g_out;
#pragma unroll
        for (int p = 0; p < 8; ++p) {
            int row = p * 16 + (tid >> 4);
            int c8  = (tid & 15) * 8;
            f32x4 v0 = *(const f32x4*)&sm.tile[row][c8];
            f32x4 v1 = *(const f32x4*)&sm.tile[row][c8 + 4];
            h16x8 hv;
#pragma unroll
            for (int j = 0; j < 4; ++j) { hv[j] = (_Float16)v0[j]; hv[j + 4] = (_Float16)v1[j]; }
            *(h16x8*)(outp + (size_t)(m0 + row) * E_DIM + e0 + c8) = hv;
        }
    }
}

// ---------------- scan pass 1: per-chunk affine composite ----------------
// grid (NCH, B), 256 threads, 4 channels per thread
__global__ void chunk_compose(const _Float16* __restrict__ g_arr,
                              const _Float16* __restrict__ c_arr,
                              float* __restrict__ Ac, float* __restrict__ Bc) {
    int d4 = threadIdx.x * 4;
    int ch = blockIdx.x;
    int b  = blockIdx.y;
    size_t base = ((size_t)b * 4096 + (size_t)ch * LCH) * 1024 + d4;
    float A[4] = {1.f, 1.f, 1.f, 1.f}, Bv[4] = {0.f, 0.f, 0.f, 0.f};
#pragma unroll 8
    for (int t = 0; t < LCH; ++t) {
        h16x4 gv = *(const h16x4*)(g_arr + base + (size_t)t * 1024);
        h16x4 cv = *(const h16x4*)(c_arr + base + (size_t)t * 1024);
#pragma unroll
        for (int j = 0; j < 4; ++j) {
            float g = (float)gv[j];
            float c = (float)cv[j];
            A[j]  = g * A[j];
            Bv[j] = g * Bv[j] + (1.f - g) * c;
        }
    }
    size_t o = ((size_t)b * NCH + ch) * 1024 + d4;
    *(f32x4*)(Ac + o) = (f32x4){A[0], A[1], A[2], A[3]};
    *(f32x4*)(Bc + o) = (f32x4){Bv[0], Bv[1], Bv[2], Bv[3]};
}

// ---------------- scan pass 2: prefix over chunks -> h at chunk entry ----------------
// 32 blocks x 256 threads = B*D threads; loads pipelined via unroll
__global__ void chunk_prefix(const float* __restrict__ Ac, const float* __restrict__ Bc,
                             const float* __restrict__ hidden, float* __restrict__ Hst) {
    int idx = blockIdx.x * 256 + threadIdx.x;   // 0..8191
    int b = idx >> 10;
    int d = idx & 1023;
    float h = hidden[b * 1024 + d];
#pragma unroll 8
    for (int ch = 0; ch < NCH; ++ch) {
        size_t o = ((size_t)b * NCH + ch) * 1024 + d;
        float A = Ac[o], Bv = Bc[o];
        Hst[o] = h;
        h = A * h + Bv;
    }
}

// ---------------- scan pass 3: apply ----------------
// grid (NCH, B), 256 threads, 4 channels per thread
__global__ void chunk_apply(const _Float16* __restrict__ g_arr,
                            const _Float16* __restrict__ c_arr,
                            const float* __restrict__ Hst,
                            float* __restrict__ out) {
    int d4 = threadIdx.x * 4;
    int ch = blockIdx.x;
    int b  = blockIdx.y;
    size_t base = ((size_t)b * 4096 + (size_t)ch * LCH) * 1024 + d4;
    size_t ho = ((size_t)b * NCH + ch) * 1024 + d4;
    f32x4 hv = *(const f32x4*)(Hst + ho);
    float h[4] = {hv[0], hv[1], hv[2], hv[3]};
#pragma unroll 4
    for (int t = 0; t < LCH; ++t) {
        size_t idx = base + (size_t)t * 1024;
        h16x4 gv = *(const h16x4*)(g_arr + idx);
        h16x4 cv = *(const h16x4*)(c_arr + idx);
#pragma unroll
        for (int j = 0; j < 4; ++j) {
            float g = (float)gv[j];
            float c = (float)cv[j];
            h[j] = g * h[j] + (1.f - g) * c;
        }
        *(f32x4*)(out + idx) = (f32x4){h[0], h[1], h[2], h[3]};
    }
}

extern "C" void kernel_launch(void* const* d_in, const int* in_sizes, int n_in,
                              void* d_out, int out_size, void* d_ws, size_t ws_size,
                              hipStream_t stream) {
    const float* x      = (const float*)d_in[0];
    const float* hidden = (const float*)d_in[1];
    const float* Wg     = (const float*)d_in[2];
    const float* bg     = (const float*)d_in[3];
    const float* Wh     = (const float*)d_in[4];
    const float* bh     = (const float*)d_in[5];
    float* out = (float*)d_out;

    char* ws = (char*)d_ws;
    const size_t WSEG = 2u * 1024u * 1024u;            // 2MB per W (fp16)
    u16* wg_h = (u16*)(ws + 0 * WSEG);
    u16* wh_h = (u16*)(ws + 1 * WSEG);                 // segs 2,3 spare (keeps offsets)
    const size_t HBYTES = (size_t)M_TOTAL * E_DIM * 2; // 64 MiB per fp16 array
    _Float16* g_arr = (_Float16*)(ws + 4 * WSEG);
    _Float16* c_arr = (_Float16*)(ws + 4 * WSEG + HBYTES);
    const size_t SSEG = (size_t)8 * NCH * 1024 * 4;    // 4 MiB per scan array
    float* Ac  = (float*)(ws + 4 * WSEG + 2 * HBYTES);
    float* Bc  = (float*)(ws + 4 * WSEG + 2 * HBYTES + SSEG);
    float* Hst = (float*)(ws + 4 * WSEG + 2 * HBYTES + 2 * SSEG);

    // 1) convert weights to fp16 (grid.y picks Wg/Wh)
    conv_w<<<dim3(1024, 2), 256, 0, stream>>>(Wg, Wh, wg_h, (1024 * 1024) / 4);

    // 2) fused dual GEMM + activation -> fp16 g, c  (e-major grid)
    gemm_act<<<dim3(E_DIM / 128, M_TOTAL / 128), 256, 0, stream>>>(
        x, wg_h, wh_h, bg, bh, g_arr, c_arr);

    // 3) chunked scan
    chunk_compose<<<dim3(NCH, 8), 256, 0, stream>>>(g_arr, c_arr, Ac, Bc);
    chunk_prefix<<<dim3(32), 256, 0, stream>>>(Ac, Bc, hidden, Hst);
    chunk_apply<<<dim3(NCH, 8), 256, 0, stream>>>(g_arr, c_arr, Hst, out);
}